// Round 9
// baseline (1206.793 us; speedup 1.0000x reference)
//
#include <hip/hip_runtime.h>
#include <stdint.h>

#define B_DIM 512
#define I_DIM 128
#define H_DIM 128
#define STEPS 511      // reference scans t = 0..T-2
#define XPLD 4         // xp inner pad: [row][u][4] f16 (r,z,n,unused)
#define HPITCH 136     // f16 units per h-tile row = 272 B (17*16B, bank-spread)

typedef __attribute__((ext_vector_type(8))) short bf16x8;
typedef __attribute__((ext_vector_type(4))) float f32x4;
typedef _Float16 half8_t __attribute__((ext_vector_type(8)));

__device__ __forceinline__ unsigned bf16rne(float f) {
  unsigned u = __float_as_uint(f);
  return (u + 0x7fffu + ((u >> 16) & 1u)) >> 16;
}
__device__ __forceinline__ short bf16s(float f) { return (short)bf16rne(f); }

// Barrier draining ONLY LDS ops; global prefetches stay in flight across it.
#define BAR_LDS() asm volatile("s_waitcnt lgkmcnt(0)\n\ts_barrier" ::: "memory")

// ---------------------------------------------------------------------------
// Fused kernel. Blocks 0..31: GRU recurrence for chunk [t0r,t1r) reading xpr.
// Blocks 32..255: xproj (MFMA GEMM) for chunk [t0x,t1x) writing xpw.
// The two roles touch disjoint buffers; xp is double-buffered across
// dispatches, so the recurrence for chunk c overlaps the projection for c+1.
// ---------------------------------------------------------------------------
__global__ __launch_bounds__(512, 2) void k_main(
    const float* __restrict__ x, const float* __restrict__ gt,
    const float* __restrict__ Wih, const float* __restrict__ Whh,
    const float* __restrict__ bih, const float* __restrict__ bhh,
    const float* __restrict__ Wdec, const float* __restrict__ bdec,
    float* __restrict__ ws_h, float* __restrict__ nll_part,
    _Float16* __restrict__ xpw, const _Float16* __restrict__ xpr,
    int t0x, int t1x, int t0r, int t1r, int first) {
  __shared__ __align__(16) char As[128 * 256];            // xproj A tile
  __shared__ __align__(16) _Float16 hT[2][16 * HPITCH];   // rec h tiles (padded)

  const int tid = threadIdx.x;
  const int lane = tid & 63;
  const int w = tid >> 6;
  const int l15 = lane & 15, l4 = lane >> 4;

  if (blockIdx.x >= 32) {
    // ======================= xproj role =======================
    // xp[rowc][u][g3] = x[rowc][:].Wih[g3*128+u][:] + bih (+bhh for r,z)
    if (t1x <= t0x) return;
    const int mh = w & 1, nh = w >> 1;

    bf16x8 bf[6][4];
    float bv[6];
#pragma unroll
    for (int nf = 0; nf < 6; ++nf) {
      const int col = nh * 96 + nf * 16 + l15;
      bv[nf] = bih[col] + (col < 256 ? bhh[col] : 0.f);
#pragma unroll
      for (int ks = 0; ks < 4; ++ks) {
        const float* wr = Wih + (size_t)col * I_DIM + ks * 32 + l4 * 8;
        const float4 wa = *(const float4*)wr;
        const float4 wb = *(const float4*)(wr + 4);
        bf16x8 b;
        b[0] = bf16s(wa.x); b[1] = bf16s(wa.y); b[2] = bf16s(wa.z); b[3] = bf16s(wa.w);
        b[4] = bf16s(wb.x); b[5] = bf16s(wb.y); b[6] = bf16s(wb.z); b[7] = bf16s(wb.w);
        bf[nf][ks] = b;
      }
    }

    const int ntile = 4 * (t1x - t0x);   // 128-row tiles in this chunk
    for (int tile = (int)blockIdx.x - 32; tile < ntile; tile += 224) {
      __syncthreads();  // previous tile's LDS reads done before restage
      const float4* xs = (const float4*)(
          x + ((size_t)t0x * B_DIM + (size_t)tile * 128) * I_DIM);
#pragma unroll
      for (int q = 0; q < 8; ++q) {
        const int fi = tid + 512 * q;
        const int arow = fi >> 5, kq = fi & 31;
        const float4 v = xs[fi];
        uint2 p;
        p.x = bf16rne(v.x) | (bf16rne(v.y) << 16);
        p.y = bf16rne(v.z) | (bf16rne(v.w) << 16);
        *(uint2*)(As + (arow << 8) + ((kq << 3) ^ ((arow & 7) << 4))) = p;
      }
      __syncthreads();

      f32x4 acc[4][6];
#pragma unroll
      for (int m = 0; m < 4; ++m)
#pragma unroll
        for (int nf = 0; nf < 6; ++nf) acc[m][nf] = (f32x4){0.f, 0.f, 0.f, 0.f};

#pragma unroll
      for (int ks = 0; ks < 4; ++ks) {
#pragma unroll
        for (int m = 0; m < 4; ++m) {
          const int arow = mh * 64 + m * 16 + l15;
          const int kbyte = ks * 64 + l4 * 16;
          const bf16x8 a =
              *(const bf16x8*)(As + (arow << 8) + (kbyte ^ ((arow & 7) << 4)));
#pragma unroll
          for (int nf = 0; nf < 6; ++nf)
            acc[m][nf] = __builtin_amdgcn_mfma_f32_16x16x32_bf16(
                a, bf[nf][ks], acc[m][nf], 0, 0, 0);
        }
      }

#pragma unroll
      for (int m = 0; m < 4; ++m) {
        const size_t rowc = (size_t)tile * 128 + mh * 64 + m * 16 + l4 * 4;
#pragma unroll
        for (int nf = 0; nf < 6; ++nf) {
          const int col = nh * 96 + nf * 16 + l15;
          const int g3 = col >> 7, uu = col & 127;
#pragma unroll
          for (int r = 0; r < 4; ++r)
            xpw[((rowc + r) * H_DIM + uu) * XPLD + g3] =
                (_Float16)(acc[m][nf][r] + bv[nf]);
        }
      }
    }
    return;
  }

  // ======================= rec role =======================
  if (t1r <= t0r) return;
  const int row0 = blockIdx.x * 16;
  const int u = w * 16 + l15;          // unit col this lane owns

  // W_hh B-fragments (f16), loop-invariant, 48 VGPR
  half8_t bfr[3][4];
#pragma unroll
  for (int g3 = 0; g3 < 3; ++g3) {
    const int col = g3 * H_DIM + u;
#pragma unroll
    for (int ks = 0; ks < 4; ++ks) {
      const float* wr = Whh + (size_t)col * H_DIM + ks * 32 + l4 * 8;
      const float4 wa = *(const float4*)wr;
      const float4 wb = *(const float4*)(wr + 4);
      half8_t b;
      b[0] = (_Float16)wa.x; b[1] = (_Float16)wa.y;
      b[2] = (_Float16)wa.z; b[3] = (_Float16)wa.w;
      b[4] = (_Float16)wb.x; b[5] = (_Float16)wb.y;
      b[6] = (_Float16)wb.z; b[7] = (_Float16)wb.w;
      bfr[g3][ks] = b;
    }
  }
  // W_dec as a B-fragment: col 0 = Wdec, cols 1..15 = 0 -> D col0 = decode
  half8_t wdB[4];
#pragma unroll
  for (int ks = 0; ks < 4; ++ks) {
    half8_t b;
#pragma unroll
    for (int j = 0; j < 8; ++j)
      b[j] = (l15 == 0) ? (_Float16)Wdec[ks * 32 + l4 * 8 + j] : (_Float16)0.f;
    wdB[ks] = b;
  }
  const float bhn_u = bhh[2 * H_DIM + u];
  const float bd0 = bdec[0];

  float h_old[4];
#pragma unroll
  for (int r = 0; r < 4; ++r) {
    const int b = l4 * 4 + r;
    h_old[r] = first ? 0.f : ws_h[(size_t)(row0 + b) * H_DIM + u];
    hT[0][b * HPITCH + u] = (_Float16)h_old[r];
  }

  // first step's xp (b64 per row: r,z,n packed)
  ushort4 xc[4];
#pragma unroll
  for (int r = 0; r < 4; ++r) {
    const size_t rowc = (size_t)(row0 + l4 * 4 + r);
    xc[r] = *(const ushort4*)&xpr[(rowc * H_DIM + u) * XPLD];
  }
  float gcur[4] = {0.f, 0.f, 0.f, 0.f};
  float nllA[4] = {0.f, 0.f, 0.f, 0.f};
  __syncthreads();

  const int nT = t1r - t0r;
#pragma unroll 1
  for (int lt = 0; lt < nT; ++lt) {
    const int s = t0r + lt;
    // prefetch next step's xp + gt (consumed next step; fly over barrier)
    const int nlt = (lt + 1 < nT) ? lt + 1 : lt;
    ushort4 xq[4];
#pragma unroll
    for (int r = 0; r < 4; ++r) {
      const size_t rowc = (size_t)nlt * B_DIM + row0 + l4 * 4 + r;
      xq[r] = *(const ushort4*)&xpr[(rowc * H_DIM + u) * XPLD];
    }
    float4 gq = {0.f, 0.f, 0.f, 0.f};
    if (l15 == 0)
      gq = *(const float4*)&gt[(size_t)(s + 1) * B_DIM + row0 + l4 * 4];

    // A-fragments: whole h(s) tile, conflict-free (272B-padded rows)
    half8_t af[4];
    const _Float16* hb = hT[lt & 1];
#pragma unroll
    for (int ks = 0; ks < 4; ++ks)
      af[ks] = *(const half8_t*)&hb[l15 * HPITCH + (ks * 4 + l4) * 8];

    // 12 MFMA matvec: preact[b][u] for r,z,n
    f32x4 aR = (f32x4){0.f, 0.f, 0.f, 0.f};
    f32x4 aZ = (f32x4){0.f, 0.f, 0.f, 0.f};
    f32x4 aN = (f32x4){0.f, 0.f, 0.f, 0.f};
#pragma unroll
    for (int ks = 0; ks < 4; ++ks) {
      aR = __builtin_amdgcn_mfma_f32_16x16x32_f16(af[ks], bfr[0][ks], aR, 0, 0, 0);
      aZ = __builtin_amdgcn_mfma_f32_16x16x32_f16(af[ks], bfr[1][ks], aZ, 0, 0, 0);
      aN = __builtin_amdgcn_mfma_f32_16x16x32_f16(af[ks], bfr[2][ks], aN, 0, 0, 0);
    }

    // decode+NLL for step s-1 via MFMA on the SAME frags (h(s) = h_new(s-1));
    // zero DS ops. All waves compute identically; wave 0 owns the result.
    if (lt > 0) {
      f32x4 aD = (f32x4){0.f, 0.f, 0.f, 0.f};
#pragma unroll
      for (int ks = 0; ks < 4; ++ks)
        aD = __builtin_amdgcn_mfma_f32_16x16x32_f16(af[ks], wdB[ks], aD, 0, 0, 0);
      if (l15 == 0) {
#pragma unroll
        for (int r = 0; r < 4; ++r) {
          const float C = 1.f / (1.f + __expf(-(aD[r] + bd0)));
          nllA[r] -= gcur[r] * __logf(C + 1e-4f) +
                     (1.f - gcur[r]) * __logf(1.f - C + 1e-4f);
        }
      }
    }

    // gate math, lane-local; write hnew into the other tile
    _Float16* hw = hT[(lt + 1) & 1];
#pragma unroll
    for (int r = 0; r < 4; ++r) {
      const float xr = (float)__builtin_bit_cast(_Float16, xc[r].x);
      const float xz = (float)__builtin_bit_cast(_Float16, xc[r].y);
      const float xn = (float)__builtin_bit_cast(_Float16, xc[r].z);
      const float rp = aR[r] + xr;   // bih+bhh_r,z folded into xp
      const float zp = aZ[r] + xz;
      const float hn = aN[r] + bhn_u;
      const float r_ = 1.f / (1.f + __expf(-rp));
      const float z_ = 1.f / (1.f + __expf(-zp));
      const float e2 = __expf(2.f * (xn + r_ * hn));
      const float n_ = 1.f - 2.f / (e2 + 1.f);
      const float hnew = (1.f - z_) * n_ + z_ * h_old[r];
      h_old[r] = hnew;
      hw[(l4 * 4 + r) * HPITCH + u] = (_Float16)hnew;
    }
#pragma unroll
    for (int r = 0; r < 4; ++r) xc[r] = xq[r];
    gcur[0] = gq.x; gcur[1] = gq.y; gcur[2] = gq.z; gcur[3] = gq.w;
    BAR_LDS();  // the ONE barrier: h(s+1) published
  }

  // epilogue: decode+NLL for step t1r-1 from h(t1r) tile (gcur = gt[t1r])
  {
    const _Float16* hb = hT[nT & 1];
    half8_t af[4];
#pragma unroll
    for (int ks = 0; ks < 4; ++ks)
      af[ks] = *(const half8_t*)&hb[l15 * HPITCH + (ks * 4 + l4) * 8];
    f32x4 aD = (f32x4){0.f, 0.f, 0.f, 0.f};
#pragma unroll
    for (int ks = 0; ks < 4; ++ks)
      aD = __builtin_amdgcn_mfma_f32_16x16x32_f16(af[ks], wdB[ks], aD, 0, 0, 0);
    if (l15 == 0) {
#pragma unroll
      for (int r = 0; r < 4; ++r) {
        const float C = 1.f / (1.f + __expf(-(aD[r] + bd0)));
        nllA[r] -= gcur[r] * __logf(C + 1e-4f) +
                   (1.f - gcur[r]) * __logf(1.f - C + 1e-4f);
      }
    }
    if (w == 0 && l15 == 0) {
#pragma unroll
      for (int r = 0; r < 4; ++r) {
        const int rr = row0 + l4 * 4 + r;
        nll_part[rr] = first ? nllA[r] : (nll_part[rr] + nllA[r]);
      }
    }
  }
#pragma unroll
  for (int r = 0; r < 4; ++r)
    ws_h[(size_t)(row0 + l4 * 4 + r) * H_DIM + u] = h_old[r];
}

// ---------------------------------------------------------------------------
__global__ __launch_bounds__(512) void k_fin(const float* __restrict__ nll_part,
                                             float* __restrict__ out) {
  __shared__ float red[8];
  const int tid = threadIdx.x;
  float v = nll_part[tid];
#pragma unroll
  for (int off = 32; off; off >>= 1) v += __shfl_down(v, off);
  if ((tid & 63) == 0) red[tid >> 6] = v;
  __syncthreads();
  if (tid == 0) {
    float s = 0.f;
#pragma unroll
    for (int i = 0; i < 8; ++i) s += red[i];
    out[0] = s * (1.f / (512.f * 512.f));
  }
}

// ---------------------------------------------------------------------------
extern "C" void kernel_launch(void* const* d_in, const int* in_sizes, int n_in,
                              void* d_out, int out_size, void* d_ws,
                              size_t ws_size, hipStream_t stream) {
  const float* x    = (const float*)d_in[0];
  const float* gt   = (const float*)d_in[1];
  const float* Wih  = (const float*)d_in[2];
  const float* Whh  = (const float*)d_in[3];
  const float* bih  = (const float*)d_in[4];
  const float* bhh  = (const float*)d_in[5];
  const float* Wdec = (const float*)d_in[6];
  const float* bdec = (const float*)d_in[7];

  // ws: [0,2KB) nll_part; [4KB,260KB) h state; then two xp chunk buffers
  float* nll_part = (float*)d_ws;
  float* ws_h = (float*)((char*)d_ws + 4096);
  const size_t xp_off = 4096 + (size_t)B_DIM * H_DIM * 4;      // 266240
  const size_t per_t = (size_t)B_DIM * H_DIM * XPLD * 2;       // 512 KB/step
  size_t avail = ws_size > xp_off ? ws_size - xp_off : 0;
  int Tc = (int)(avail / (2 * per_t));
  if (Tc > 64) Tc = 64;
  if (Tc < 1) Tc = 1;
  const int nch = (STEPS + Tc - 1) / Tc;
  _Float16* buf0 = (_Float16*)((char*)d_ws + xp_off);
  _Float16* buf1 = (_Float16*)((char*)d_ws + xp_off + (size_t)Tc * per_t);

  // Dispatch d: xproj chunk d into buf[d&1]  ||  rec chunk d-1 from buf[(d-1)&1]
  for (int d = 0; d <= nch; ++d) {
    int t0x = d * Tc, t1x = t0x + Tc;
    if (t1x > STEPS) t1x = STEPS;
    if (d >= nch) { t0x = 0; t1x = 0; }
    int t0r = (d - 1) * Tc, t1r = t0r + Tc;
    if (t1r > STEPS) t1r = STEPS;
    if (d < 1) { t0r = 0; t1r = 0; }
    _Float16* xw = (d & 1) ? buf1 : buf0;
    const _Float16* xr = (d & 1) ? buf0 : buf1;
    k_main<<<dim3(256), dim3(512), 0, stream>>>(
        x, gt, Wih, Whh, bih, bhh, Wdec, bdec, ws_h, nll_part,
        xw, xr, t0x, t1x, t0r, t1r, (d == 1) ? 1 : 0);
  }
  k_fin<<<dim3(1), dim3(512), 0, stream>>>(nll_part, (float*)d_out);
}

// Round 11
// 976.847 us; speedup vs baseline: 1.2354x; 1.2354x over previous
//
#include <hip/hip_runtime.h>
#include <stdint.h>

#define B_DIM 512
#define I_DIM 128
#define H_DIM 128
#define G_DIM 384
#define STEPS 511      // reference scans t = 0..T-2

typedef __attribute__((ext_vector_type(8))) short bf16x8;
typedef __attribute__((ext_vector_type(4))) float f32x4;
typedef _Float16 half2_t __attribute__((ext_vector_type(2)));
typedef _Float16 half8_t __attribute__((ext_vector_type(8)));

__device__ __forceinline__ unsigned bf16rne(float f) {
  unsigned u = __float_as_uint(f);
  return (u + 0x7fffu + ((u >> 16) & 1u)) >> 16;
}
__device__ __forceinline__ short bf16s(float f) { return (short)bf16rne(f); }
__device__ __forceinline__ unsigned pack_h2(float a, float b) {
  half2_t p; p.x = (_Float16)a; p.y = (_Float16)b;
  return __builtin_bit_cast(unsigned, p);
}

// Barrier draining ONLY LDS ops; global prefetches stay in flight across it.
#define BAR_LDS() asm volatile("s_waitcnt lgkmcnt(0)\n\ts_barrier" ::: "memory")

// ---------------------------------------------------------------------------
// Fused kernel. Blocks 0..31: GRU recurrence chunk [t0r,t1r) reading planar
// xpr (4 work waves + 4 barrier-idler waves). Blocks 32..255: xproj MFMA GEMM
// chunk [t0x,t1x) writing planar xpw. xp double-buffered across dispatches.
//
// rec: 16 rows/block. Wave w<4 owns units 32w..32w+31 as ADJACENT PAIRS:
// MFMA tile c in {0,1} has cols j -> unit 32w+2j+c, so lane l15 holds the
// preacts for units (u0,u0+1), u0=32w+2*l15, rows b=4*l4+r. W_hh B-frags
// f16 in 96 VGPR. h tile: [16 rows][128 u] f16, 256B rows, 16B blocks XOR-
// swizzled by (kblk ^ row) -> conflict-minimal b128 reads, 2-way b32 writes.
// Per step: 12 b32 xp loads + 4 b128 h reads + 24 MFMA + lane-local gate
// math + 4 b32 h writes + ONE lgkm-only barrier. Decode via 4 extra MFMAs
// vs W_dec col-0 fragment on wave 0 only (zero DS ops).
// ---------------------------------------------------------------------------
__global__ __launch_bounds__(512, 1) void k_main(
    const float* __restrict__ x, const float* __restrict__ gt,
    const float* __restrict__ Wih, const float* __restrict__ Whh,
    const float* __restrict__ bih, const float* __restrict__ bhh,
    const float* __restrict__ Wdec, const float* __restrict__ bdec,
    float* __restrict__ ws_h, float* __restrict__ nll_part,
    _Float16* __restrict__ xpw, const _Float16* __restrict__ xpr,
    int t0x, int t1x, int t0r, int t1r, int first) {
  __shared__ __align__(16) char As[128 * 256];        // xproj A tile (32 KB)
  __shared__ __align__(16) _Float16 hT[2][16 * 128];  // rec h tiles (8 KB)

  const int tid = threadIdx.x;
  const int lane = tid & 63;
  const int w = tid >> 6;
  const int l15 = lane & 15, l4 = lane >> 4;

  if (blockIdx.x >= 32) {
    // ======================= xproj role =======================
    if (t1x <= t0x) return;
    const int mh = w & 1, nh = w >> 1;

    bf16x8 bf[6][4];
    float bv[6];
#pragma unroll
    for (int nf = 0; nf < 6; ++nf) {
      const int col = nh * 96 + nf * 16 + l15;
      bv[nf] = bih[col] + (col < 256 ? bhh[col] : 0.f);  // fold bhh for r,z
#pragma unroll
      for (int ks = 0; ks < 4; ++ks) {
        const float* wr = Wih + (size_t)col * I_DIM + ks * 32 + l4 * 8;
        const float4 wa = *(const float4*)wr;
        const float4 wb = *(const float4*)(wr + 4);
        bf16x8 b;
        b[0] = bf16s(wa.x); b[1] = bf16s(wa.y); b[2] = bf16s(wa.z); b[3] = bf16s(wa.w);
        b[4] = bf16s(wb.x); b[5] = bf16s(wb.y); b[6] = bf16s(wb.z); b[7] = bf16s(wb.w);
        bf[nf][ks] = b;
      }
    }

    const int ntile = 4 * (t1x - t0x);
    for (int tile = (int)blockIdx.x - 32; tile < ntile; tile += 224) {
      __syncthreads();
      const float4* xs = (const float4*)(
          x + ((size_t)t0x * B_DIM + (size_t)tile * 128) * I_DIM);
#pragma unroll
      for (int q = 0; q < 8; ++q) {
        const int fi = tid + 512 * q;
        const int arow = fi >> 5, kq = fi & 31;
        const float4 v = xs[fi];
        uint2 p;
        p.x = bf16rne(v.x) | (bf16rne(v.y) << 16);
        p.y = bf16rne(v.z) | (bf16rne(v.w) << 16);
        *(uint2*)(As + (arow << 8) + ((kq << 3) ^ ((arow & 7) << 4))) = p;
      }
      __syncthreads();

      f32x4 acc[4][6];
#pragma unroll
      for (int m = 0; m < 4; ++m)
#pragma unroll
        for (int nf = 0; nf < 6; ++nf) acc[m][nf] = (f32x4){0.f, 0.f, 0.f, 0.f};

#pragma unroll
      for (int ks = 0; ks < 4; ++ks) {
#pragma unroll
        for (int m = 0; m < 4; ++m) {
          const int arow = mh * 64 + m * 16 + l15;
          const int kbyte = ks * 64 + l4 * 16;
          const bf16x8 a =
              *(const bf16x8*)(As + (arow << 8) + (kbyte ^ ((arow & 7) << 4)));
#pragma unroll
          for (int nf = 0; nf < 6; ++nf)
            acc[m][nf] = __builtin_amdgcn_mfma_f32_16x16x32_bf16(
                a, bf[nf][ks], acc[m][nf], 0, 0, 0);
        }
      }

#pragma unroll
      for (int m = 0; m < 4; ++m) {
        const size_t rowc = (size_t)tile * 128 + mh * 64 + m * 16 + l4 * 4;
#pragma unroll
        for (int nf = 0; nf < 6; ++nf) {
          const int col = nh * 96 + nf * 16 + l15;
#pragma unroll
          for (int r = 0; r < 4; ++r)
            xpw[(rowc + r) * G_DIM + col] = (_Float16)(acc[m][nf][r] + bv[nf]);
        }
      }
    }
    return;
  }

  // ======================= rec role =======================
  if (t1r <= t0r) return;
  const int nT = t1r - t0r;

  // Waves 4..7: barrier-matched idlers (must NOT touch Whh/hT — r10's bug).
  if (w >= 4) {
    __syncthreads();
    for (int lt = 0; lt < nT; ++lt) BAR_LDS();
    return;
  }

  const int row0 = blockIdx.x * 16;
  const int u0 = w * 32 + 2 * l15;        // lane's unit pair (u0, u0+1)
  const int ublk = u0 >> 3;               // 16B block index of the pair
  const int uoff = (u0 & 7) * 2;          // byte offset within block

  // W_hh B-fragments, pair-permuted: tile c cols j -> unit 32w+2j+c
  half8_t bfr[3][2][4];
#pragma unroll
  for (int g3 = 0; g3 < 3; ++g3)
#pragma unroll
    for (int c = 0; c < 2; ++c) {
      const int rowW = g3 * H_DIM + u0 + c;
#pragma unroll
      for (int ks = 0; ks < 4; ++ks) {
        const float* wr = Whh + (size_t)rowW * H_DIM + ks * 32 + l4 * 8;
        const float4 wa = *(const float4*)wr;
        const float4 wb = *(const float4*)(wr + 4);
        half8_t b;
        b[0] = (_Float16)wa.x; b[1] = (_Float16)wa.y;
        b[2] = (_Float16)wa.z; b[3] = (_Float16)wa.w;
        b[4] = (_Float16)wb.x; b[5] = (_Float16)wb.y;
        b[6] = (_Float16)wb.z; b[7] = (_Float16)wb.w;
        bfr[g3][c][ks] = b;
      }
    }
  // W_dec as B-fragment col 0 (decode via MFMA; wave 0 only uses it)
  half8_t wdB[4];
#pragma unroll
  for (int ks = 0; ks < 4; ++ks) {
    half8_t b;
#pragma unroll
    for (int j = 0; j < 8; ++j)
      b[j] = (l15 == 0) ? (_Float16)Wdec[ks * 32 + l4 * 8 + j] : (_Float16)0.f;
    wdB[ks] = b;
  }
  const float bhnA = bhh[2 * H_DIM + u0];
  const float bhnB = bhh[2 * H_DIM + u0 + 1];
  const float bd0 = bdec[0];

  // init h (fp32 regs) + h tile buffer 0 (swizzled)
  float hA[4], hB[4];
#pragma unroll
  for (int r = 0; r < 4; ++r) {
    const int b = 4 * l4 + r;
    hA[r] = first ? 0.f : ws_h[(size_t)(row0 + b) * H_DIM + u0];
    hB[r] = first ? 0.f : ws_h[(size_t)(row0 + b) * H_DIM + u0 + 1];
    *(unsigned*)((char*)hT[0] + b * 256 + ((ublk ^ b) << 4) + uoff) =
        pack_h2(hA[r], hB[r]);
  }

  // first step's xp (planar; pair adjacent -> b32)
  unsigned xc[4][3];
#pragma unroll
  for (int r = 0; r < 4; ++r)
#pragma unroll
    for (int g3 = 0; g3 < 3; ++g3)
      xc[r][g3] = *(const unsigned*)&xpr[((size_t)(row0 + 4 * l4 + r)) * G_DIM +
                                         g3 * H_DIM + u0];
  float gcur[4] = {0.f, 0.f, 0.f, 0.f};
  float nllA[4] = {0.f, 0.f, 0.f, 0.f};
  __syncthreads();

#pragma unroll 1
  for (int lt = 0; lt < nT; ++lt) {
    const int s = t0r + lt;
    // prefetch next step's xp + gt (consumed next iter; fly over barrier)
    const int nlt = (lt + 1 < nT) ? lt + 1 : lt;
    unsigned xq[4][3];
#pragma unroll
    for (int r = 0; r < 4; ++r)
#pragma unroll
      for (int g3 = 0; g3 < 3; ++g3)
        xq[r][g3] = *(const unsigned*)&xpr[((size_t)nlt * B_DIM + row0 +
                                            4 * l4 + r) * G_DIM +
                                           g3 * H_DIM + u0];
    float4 gq = {0.f, 0.f, 0.f, 0.f};
    if (w == 0 && l15 == 0)
      gq = *(const float4*)&gt[(size_t)(s + 1) * B_DIM + row0 + 4 * l4];

    // A-fragments: h(s) tile, XOR-swizzled
    half8_t af[4];
    const char* hbp = (const char*)hT[lt & 1];
#pragma unroll
    for (int ks = 0; ks < 4; ++ks)
      af[ks] = *(const half8_t*)(hbp + l15 * 256 +
                                 ((((ks << 2) | l4) ^ l15) << 4));

    // decode + NLL for step s-1 (h(s) = hnew(s-1)); wave 0 only, zero DS
    if (w == 0 && lt > 0) {
      f32x4 aD = (f32x4){0.f, 0.f, 0.f, 0.f};
#pragma unroll
      for (int ks = 0; ks < 4; ++ks)
        aD = __builtin_amdgcn_mfma_f32_16x16x32_f16(af[ks], wdB[ks], aD, 0, 0, 0);
      if (l15 == 0) {
#pragma unroll
        for (int r = 0; r < 4; ++r) {
          const float C = 1.f / (1.f + __expf(-(aD[r] + bd0)));
          nllA[r] -= gcur[r] * __logf(C + 1e-4f) +
                     (1.f - gcur[r]) * __logf(1.f - C + 1e-4f);
        }
      }
    }

    // 24 MFMA: preacts for r,z,n x unit-pair tiles
    f32x4 aR0 = (f32x4){0.f,0.f,0.f,0.f}, aR1 = (f32x4){0.f,0.f,0.f,0.f};
    f32x4 aZ0 = (f32x4){0.f,0.f,0.f,0.f}, aZ1 = (f32x4){0.f,0.f,0.f,0.f};
    f32x4 aN0 = (f32x4){0.f,0.f,0.f,0.f}, aN1 = (f32x4){0.f,0.f,0.f,0.f};
#pragma unroll
    for (int ks = 0; ks < 4; ++ks) {
      aR0 = __builtin_amdgcn_mfma_f32_16x16x32_f16(af[ks], bfr[0][0][ks], aR0, 0, 0, 0);
      aR1 = __builtin_amdgcn_mfma_f32_16x16x32_f16(af[ks], bfr[0][1][ks], aR1, 0, 0, 0);
      aZ0 = __builtin_amdgcn_mfma_f32_16x16x32_f16(af[ks], bfr[1][0][ks], aZ0, 0, 0, 0);
      aZ1 = __builtin_amdgcn_mfma_f32_16x16x32_f16(af[ks], bfr[1][1][ks], aZ1, 0, 0, 0);
      aN0 = __builtin_amdgcn_mfma_f32_16x16x32_f16(af[ks], bfr[2][0][ks], aN0, 0, 0, 0);
      aN1 = __builtin_amdgcn_mfma_f32_16x16x32_f16(af[ks], bfr[2][1][ks], aN1, 0, 0, 0);
    }

    // gate math, lane-local; write hnew pairs (b32) into other tile
    char* hw = (char*)hT[(lt + 1) & 1];
#pragma unroll
    for (int r = 0; r < 4; ++r) {
      const half2_t x0 = __builtin_bit_cast(half2_t, xc[r][0]);
      const half2_t x1 = __builtin_bit_cast(half2_t, xc[r][1]);
      const half2_t x2 = __builtin_bit_cast(half2_t, xc[r][2]);
      const float rpA = aR0[r] + (float)x0.x, rpB = aR1[r] + (float)x0.y;
      const float zpA = aZ0[r] + (float)x1.x, zpB = aZ1[r] + (float)x1.y;
      const float hnA = aN0[r] + bhnA,        hnB = aN1[r] + bhnB;
      const float rA = 1.f / (1.f + __expf(-rpA));
      const float rB = 1.f / (1.f + __expf(-rpB));
      const float zA = 1.f / (1.f + __expf(-zpA));
      const float zB = 1.f / (1.f + __expf(-zpB));
      const float eA = __expf(2.f * ((float)x2.x + rA * hnA));
      const float eB = __expf(2.f * ((float)x2.y + rB * hnB));
      const float nA = 1.f - 2.f / (eA + 1.f);
      const float nB = 1.f - 2.f / (eB + 1.f);
      const float hnewA = (1.f - zA) * nA + zA * hA[r];
      const float hnewB = (1.f - zB) * nB + zB * hB[r];
      hA[r] = hnewA; hB[r] = hnewB;
      const int b = 4 * l4 + r;
      *(unsigned*)(hw + b * 256 + ((ublk ^ b) << 4) + uoff) =
          pack_h2(hnewA, hnewB);
    }
#pragma unroll
    for (int r = 0; r < 4; ++r)
#pragma unroll
      for (int g3 = 0; g3 < 3; ++g3) xc[r][g3] = xq[r][g3];
    gcur[0] = gq.x; gcur[1] = gq.y; gcur[2] = gq.z; gcur[3] = gq.w;
    BAR_LDS();  // the ONE barrier per step
  }

  // epilogue: decode + NLL for step t1r-1 from final h tile (gcur = gt[t1r])
  {
    const char* hbp = (const char*)hT[nT & 1];
    if (w == 0) {
      half8_t af[4];
#pragma unroll
      for (int ks = 0; ks < 4; ++ks)
        af[ks] = *(const half8_t*)(hbp + l15 * 256 +
                                   ((((ks << 2) | l4) ^ l15) << 4));
      f32x4 aD = (f32x4){0.f, 0.f, 0.f, 0.f};
#pragma unroll
      for (int ks = 0; ks < 4; ++ks)
        aD = __builtin_amdgcn_mfma_f32_16x16x32_f16(af[ks], wdB[ks], aD, 0, 0, 0);
      if (l15 == 0) {
#pragma unroll
        for (int r = 0; r < 4; ++r) {
          const float C = 1.f / (1.f + __expf(-(aD[r] + bd0)));
          nllA[r] -= gcur[r] * __logf(C + 1e-4f) +
                     (1.f - gcur[r]) * __logf(1.f - C + 1e-4f);
          const int rr = row0 + 4 * l4 + r;
          nll_part[rr] = first ? nllA[r] : (nll_part[rr] + nllA[r]);
        }
      }
    }
  }
#pragma unroll
  for (int r = 0; r < 4; ++r) {
    const int b = 4 * l4 + r;
    ws_h[(size_t)(row0 + b) * H_DIM + u0] = hA[r];
    ws_h[(size_t)(row0 + b) * H_DIM + u0 + 1] = hB[r];
  }
}

// ---------------------------------------------------------------------------
__global__ __launch_bounds__(512) void k_fin(const float* __restrict__ nll_part,
                                             float* __restrict__ out) {
  __shared__ float red[8];
  const int tid = threadIdx.x;
  float v = nll_part[tid];
#pragma unroll
  for (int off = 32; off; off >>= 1) v += __shfl_down(v, off);
  if ((tid & 63) == 0) red[tid >> 6] = v;
  __syncthreads();
  if (tid == 0) {
    float s = 0.f;
#pragma unroll
    for (int i = 0; i < 8; ++i) s += red[i];
    out[0] = s * (1.f / (512.f * 512.f));
  }
}

// ---------------------------------------------------------------------------
extern "C" void kernel_launch(void* const* d_in, const int* in_sizes, int n_in,
                              void* d_out, int out_size, void* d_ws,
                              size_t ws_size, hipStream_t stream) {
  const float* x    = (const float*)d_in[0];
  const float* gt   = (const float*)d_in[1];
  const float* Wih  = (const float*)d_in[2];
  const float* Whh  = (const float*)d_in[3];
  const float* bih  = (const float*)d_in[4];
  const float* bhh  = (const float*)d_in[5];
  const float* Wdec = (const float*)d_in[6];
  const float* bdec = (const float*)d_in[7];

  // ws: [0,2KB) nll_part; [4KB,260KB) h state; then two planar xp buffers
  float* nll_part = (float*)d_ws;
  float* ws_h = (float*)((char*)d_ws + 4096);
  const size_t xp_off = 4096 + (size_t)B_DIM * H_DIM * 4;   // 266240
  const size_t per_t = (size_t)B_DIM * G_DIM * 2;           // 384 KB/step f16
  size_t avail = ws_size > xp_off ? ws_size - xp_off : 0;
  int Tc = (int)(avail / (2 * per_t));
  if (Tc > 64) Tc = 64;
  if (Tc < 1) Tc = 1;
  const int nch = (STEPS + Tc - 1) / Tc;
  _Float16* buf0 = (_Float16*)((char*)d_ws + xp_off);
  _Float16* buf1 = (_Float16*)((char*)d_ws + xp_off + (size_t)Tc * per_t);

  // Dispatch d: xproj chunk d -> buf[d&1]  ||  rec chunk d-1 <- buf[(d-1)&1]
  for (int d = 0; d <= nch; ++d) {
    int t0x = d * Tc, t1x = t0x + Tc;
    if (t1x > STEPS) t1x = STEPS;
    if (d >= nch) { t0x = 0; t1x = 0; }
    int t0r = (d - 1) * Tc, t1r = t0r + Tc;
    if (t1r > STEPS) t1r = STEPS;
    if (d < 1) { t0r = 0; t1r = 0; }
    _Float16* xw = (d & 1) ? buf1 : buf0;
    const _Float16* xr = (d & 1) ? buf0 : buf1;
    k_main<<<dim3(256), dim3(512), 0, stream>>>(
        x, gt, Wih, Whh, bih, bhh, Wdec, bdec, ws_h, nll_part,
        xw, xr, t0x, t1x, t0r, t1r, (d == 1) ? 1 : 0);
  }
  k_fin<<<dim3(1), dim3(512), 0, stream>>>(nll_part, (float*)d_out);
}

// Round 12
// 842.209 us; speedup vs baseline: 1.4329x; 1.1599x over previous
//
#include <hip/hip_runtime.h>
#include <stdint.h>

#define B_DIM 512
#define I_DIM 128
#define H_DIM 128
#define NSTEP 511   // reference scans t = 0..T-2

typedef __attribute__((ext_vector_type(4))) float f32x4;
typedef _Float16 half2_t __attribute__((ext_vector_type(2)));
typedef _Float16 half8_t __attribute__((ext_vector_type(8)));

// Barrier draining ONLY LDS ops; global prefetches stay in flight across it.
#define BAR_LDS() asm volatile("s_waitcnt lgkmcnt(0)\n\ts_barrier" ::: "memory")

#define MFMA16(A, B, C) __builtin_amdgcn_mfma_f32_16x16x32_f16(A, B, C, 0, 0, 0)

// ---------------------------------------------------------------------------
// Persistent fused GRU: 32 blocks x 16 batch rows, 512 threads (8 work
// waves, 2/SIMD). ALL 511 steps in one dispatch; h never leaves the block.
//
// Wave w owns units 16w..16w+15. Per lane: unit u = 16w + l15, rows 4*l4+r.
// B-fragments (f16, registers, loaded once): Whh rows {u,128+u,256+u} (48
// VGPR) + Wih same (48) + Wdec col-0 frag (8).
// Per step: 1 float4 global x(s+1) load -> staged f16 into double-buffered
// xT; 8 ds_read_b128 A-frags (h(s), x(s) tiles, XOR-swizzled (blk^row));
// 24 MFMA (r,z combine x+h into one accumulator; n keeps x/h split for the
// r* term); lane-local gate math; 4 ds_write_b16 hnew; ONE lgkm-only
// barrier. Decode+NLL for h(s) via 4 extra MFMAs on wave 0 (zero DS ops),
// gt preloaded to LDS once.
// ---------------------------------------------------------------------------
__global__ __launch_bounds__(512, 2) void k_rec(
    const float* __restrict__ x, const float* __restrict__ gt,
    const float* __restrict__ Wih, const float* __restrict__ Whh,
    const float* __restrict__ bih, const float* __restrict__ bhh,
    const float* __restrict__ Wdec, const float* __restrict__ bdec,
    float* __restrict__ nll_part) {
  __shared__ __align__(16) _Float16 hT[2][16 * 128];  // 8 KB, dbuf h tiles
  __shared__ __align__(16) _Float16 xT[2][16 * 128];  // 8 KB, dbuf x tiles
  __shared__ float gl[NSTEP * 16];                    // 32 KB gt slice

  const int tid = threadIdx.x;
  const int lane = tid & 63;
  const int w = tid >> 6;
  const int l15 = lane & 15, l4 = lane >> 4;
  const int row0 = blockIdx.x * 16;
  const int u = 16 * w + l15;          // unit this lane owns

  // x-staging identity: thread -> (row, 4-float chunk); swizzled byte addr
  const int sxr = tid >> 5;            // row in [0,16)
  const int scq = tid & 31;            // col chunk
  const int sbyte = sxr * 256 + (((scq >> 1) ^ sxr) << 4) + (scq & 1) * 8;

  // ---- one-time: B-fragments (f16) for Whh and Wih ----
  half8_t bh[3][4], bx[3][4];
#pragma unroll
  for (int g3 = 0; g3 < 3; ++g3) {
#pragma unroll
    for (int ks = 0; ks < 4; ++ks) {
      const size_t off = (size_t)(g3 * H_DIM + u) * H_DIM + ks * 32 + l4 * 8;
      float4 a = *(const float4*)(Whh + off);
      float4 b = *(const float4*)(Whh + off + 4);
      half8_t v;
      v[0] = (_Float16)a.x; v[1] = (_Float16)a.y;
      v[2] = (_Float16)a.z; v[3] = (_Float16)a.w;
      v[4] = (_Float16)b.x; v[5] = (_Float16)b.y;
      v[6] = (_Float16)b.z; v[7] = (_Float16)b.w;
      bh[g3][ks] = v;
      a = *(const float4*)(Wih + off);
      b = *(const float4*)(Wih + off + 4);
      v[0] = (_Float16)a.x; v[1] = (_Float16)a.y;
      v[2] = (_Float16)a.z; v[3] = (_Float16)a.w;
      v[4] = (_Float16)b.x; v[5] = (_Float16)b.y;
      v[6] = (_Float16)b.z; v[7] = (_Float16)b.w;
      bx[g3][ks] = v;
    }
  }
  // W_dec as B-fragment col 0 (decode via MFMA on wave 0)
  half8_t wdB[4];
#pragma unroll
  for (int ks = 0; ks < 4; ++ks) {
    half8_t v;
#pragma unroll
    for (int j = 0; j < 8; ++j)
      v[j] = (l15 == 0) ? (_Float16)Wdec[ks * 32 + l4 * 8 + j] : (_Float16)0.f;
    wdB[ks] = v;
  }
  const float brz0 = bih[u] + bhh[u];                    // r-gate bias
  const float brz1 = bih[H_DIM + u] + bhh[H_DIM + u];    // z-gate bias
  const float bxn = bih[2 * H_DIM + u];                  // n-gate x-side
  const float bhn = bhh[2 * H_DIM + u];                  // n-gate h-side
  const float bd0 = bdec[0];

  // ---- gt preload: gl[s*16 + c] = gt[s+1][row0+c] ----
#pragma unroll
  for (int q = 0; q < 16; ++q) {
    const int idx = tid + 512 * q;
    if (idx < NSTEP * 16)
      gl[idx] = gt[(size_t)((idx >> 4) + 1) * B_DIM + row0 + (idx & 15)];
  }

  // ---- zero h(0) tile; stage x(0) ----
  {
    *(uint2*)((char*)hT[0] + sbyte) = (uint2){0u, 0u};
    const float4 xv = *(const float4*)&x[((size_t)row0 + sxr) * I_DIM + 4 * scq];
    half2_t p0, p1;
    p0.x = (_Float16)xv.x; p0.y = (_Float16)xv.y;
    p1.x = (_Float16)xv.z; p1.y = (_Float16)xv.w;
    uint2 pk;
    pk.x = __builtin_bit_cast(unsigned, p0);
    pk.y = __builtin_bit_cast(unsigned, p1);
    *(uint2*)((char*)xT[0] + sbyte) = pk;
  }
  float h_old[4] = {0.f, 0.f, 0.f, 0.f};
  float nllA[4] = {0.f, 0.f, 0.f, 0.f};
  __syncthreads();

#pragma unroll 1
  for (int s = 0; s < NSTEP; ++s) {
    // prefetch x(s+1): 1 float4/thread; consumed at stage-write below
    const float4 xv =
        *(const float4*)&x[((size_t)(s + 1) * B_DIM + row0 + sxr) * I_DIM + 4 * scq];

    // A-fragments for h(s) and x(s), XOR-swizzled (blk ^ row)
    const char* hb = (const char*)hT[s & 1];
    const char* xb = (const char*)xT[s & 1];
    half8_t ah[4], ax[4];
#pragma unroll
    for (int ks = 0; ks < 4; ++ks) {
      const int ab = l15 * 256 + ((((ks << 2) | l4) ^ l15) << 4);
      ah[ks] = *(const half8_t*)(hb + ab);
      ax[ks] = *(const half8_t*)(xb + ab);
    }

    // decode + NLL for h(s) vs gt[s] (pairs k=1..510 here; 511 in epilogue)
    if (w == 0 && s > 0) {
      f32x4 aD = (f32x4){0.f, 0.f, 0.f, 0.f};
#pragma unroll
      for (int ks = 0; ks < 4; ++ks) aD = MFMA16(ah[ks], wdB[ks], aD);
      if (l15 == 0) {
#pragma unroll
        for (int r = 0; r < 4; ++r) {
          const float C = 1.f / (1.f + __expf(-(aD[r] + bd0)));
          const float g = gl[(s - 1) * 16 + 4 * l4 + r];
          nllA[r] -= g * __logf(C + 1e-4f) +
                     (1.f - g) * __logf(1.f - C + 1e-4f);
        }
      }
    }

    // 24 MFMA: r,z fold x+h into one accumulator; n keeps parts split
    f32x4 aR = (f32x4){0.f, 0.f, 0.f, 0.f};
    f32x4 aZ = (f32x4){0.f, 0.f, 0.f, 0.f};
    f32x4 aNh = (f32x4){0.f, 0.f, 0.f, 0.f};
    f32x4 aNx = (f32x4){0.f, 0.f, 0.f, 0.f};
#pragma unroll
    for (int ks = 0; ks < 4; ++ks) {
      aR = MFMA16(ah[ks], bh[0][ks], aR);
      aR = MFMA16(ax[ks], bx[0][ks], aR);
      aZ = MFMA16(ah[ks], bh[1][ks], aZ);
      aZ = MFMA16(ax[ks], bx[1][ks], aZ);
      aNh = MFMA16(ah[ks], bh[2][ks], aNh);
      aNx = MFMA16(ax[ks], bx[2][ks], aNx);
    }

    // gate math, lane-local; write hnew (b16) into the other h tile
    char* hw = (char*)hT[(s + 1) & 1];
#pragma unroll
    for (int r = 0; r < 4; ++r) {
      const float rp = aR[r] + brz0;
      const float zp = aZ[r] + brz1;
      const float r_ = 1.f / (1.f + __expf(-rp));
      const float z_ = 1.f / (1.f + __expf(-zp));
      const float a2 = (aNx[r] + bxn) + r_ * (aNh[r] + bhn);
      const float e2 = __expf(2.f * a2);
      const float n_ = 1.f - 2.f / (e2 + 1.f);
      const float hnew = (1.f - z_) * n_ + z_ * h_old[r];
      h_old[r] = hnew;
      const int b = 4 * l4 + r;
      *(_Float16*)(hw + b * 256 + (((u >> 3) ^ b) << 4) + (u & 7) * 2) =
          (_Float16)hnew;
    }

    // stage x(s+1) into the other x tile (vmcnt wait lands here, late)
    {
      half2_t p0, p1;
      p0.x = (_Float16)xv.x; p0.y = (_Float16)xv.y;
      p1.x = (_Float16)xv.z; p1.y = (_Float16)xv.w;
      uint2 pk;
      pk.x = __builtin_bit_cast(unsigned, p0);
      pk.y = __builtin_bit_cast(unsigned, p1);
      *(uint2*)((char*)xT[(s + 1) & 1] + sbyte) = pk;
    }
    BAR_LDS();  // the ONE barrier: h(s+1) + x(s+1) published
  }

  // ---- epilogue: decode h(511) vs gt[511]; write per-row NLL ----
  if (w == 0) {
    const char* hb = (const char*)hT[NSTEP & 1];
    half8_t ah[4];
#pragma unroll
    for (int ks = 0; ks < 4; ++ks)
      ah[ks] = *(const half8_t*)(hb + l15 * 256 +
                                 ((((ks << 2) | l4) ^ l15) << 4));
    f32x4 aD = (f32x4){0.f, 0.f, 0.f, 0.f};
#pragma unroll
    for (int ks = 0; ks < 4; ++ks) aD = MFMA16(ah[ks], wdB[ks], aD);
    if (l15 == 0) {
#pragma unroll
      for (int r = 0; r < 4; ++r) {
        const float C = 1.f / (1.f + __expf(-(aD[r] + bd0)));
        const float g = gl[(NSTEP - 1) * 16 + 4 * l4 + r];
        nllA[r] -= g * __logf(C + 1e-4f) +
                   (1.f - g) * __logf(1.f - C + 1e-4f);
        nll_part[row0 + 4 * l4 + r] = nllA[r];
      }
    }
  }
}

// ---------------------------------------------------------------------------
__global__ __launch_bounds__(512) void k_fin(const float* __restrict__ nll_part,
                                             float* __restrict__ out) {
  __shared__ float red[8];
  const int tid = threadIdx.x;
  float v = nll_part[tid];
#pragma unroll
  for (int off = 32; off; off >>= 1) v += __shfl_down(v, off);
  if ((tid & 63) == 0) red[tid >> 6] = v;
  __syncthreads();
  if (tid == 0) {
    float s = 0.f;
#pragma unroll
    for (int i = 0; i < 8; ++i) s += red[i];
    out[0] = s * (1.f / (512.f * 512.f));
  }
}

// ---------------------------------------------------------------------------
extern "C" void kernel_launch(void* const* d_in, const int* in_sizes, int n_in,
                              void* d_out, int out_size, void* d_ws,
                              size_t ws_size, hipStream_t stream) {
  const float* x    = (const float*)d_in[0];
  const float* gt   = (const float*)d_in[1];
  const float* Wih  = (const float*)d_in[2];
  const float* Whh  = (const float*)d_in[3];
  const float* bih  = (const float*)d_in[4];
  const float* bhh  = (const float*)d_in[5];
  const float* Wdec = (const float*)d_in[6];
  const float* bdec = (const float*)d_in[7];

  float* nll_part = (float*)d_ws;  // 512 floats, each written exactly once

  k_rec<<<dim3(32), dim3(512), 0, stream>>>(
      x, gt, Wih, Whh, bih, bhh, Wdec, bdec, nll_part);
  k_fin<<<dim3(1), dim3(512), 0, stream>>>(nll_part, (float*)d_out);
}